// Round 3
// baseline (345.537 us; speedup 1.0000x reference)
//
#include <hip/hip_runtime.h>
#include <math.h>

// Problem constants: B=8, N=2048, D=512, S=4096
#define BATCH 8
#define NNODES 2048
#define DDIM 512
#define SWAPS 4096
#define M_TOTAL (BATCH * SWAPS)   // 32768
#define K1 2048
#define N1 512
#define K2 512
#define N2 256

typedef __attribute__((ext_vector_type(8))) __bf16 bf16x8;   // MFMA A/B frag
typedef __attribute__((ext_vector_type(4))) float f32x4;      // MFMA C/D frag
typedef unsigned short ushort_t;

__device__ __forceinline__ float gelu_exact(float x) {
    return 0.5f * x * (1.0f + erff(x * 0.70710678118654752440f));
}
__device__ __forceinline__ float softplus_f(float x) {
    return fmaxf(x, 0.0f) + log1pf(expf(-fabsf(x)));
}
__device__ __forceinline__ unsigned short f2bf(float f) {
    unsigned int u = __builtin_bit_cast(unsigned int, f);
    u += 0x7FFFu + ((u >> 16) & 1u);
    return (unsigned short)(u >> 16);
}
__device__ __forceinline__ void glds16(const void* g, void* l) {
    __builtin_amdgcn_global_load_lds(
        (const __attribute__((address_space(1))) void*)g,
        (__attribute__((address_space(3))) void*)l, 16, 0, 0);
}

// ---------------------------------------------------------------------------
// convert: h -> h_bf;  W1[k][n] -> W1t[n][k] bf16;  W2 -> W2t bf16
// ---------------------------------------------------------------------------
__global__ __launch_bounds__(256) void convert_kernel(
    const float* __restrict__ h, const float* __restrict__ W1,
    const float* __restrict__ W2, ushort_t* __restrict__ h_bf,
    ushort_t* __restrict__ W1t, ushort_t* __restrict__ W2t)
{
    const int bid = blockIdx.x;
    if (bid < 8192) {
        size_t i = ((size_t)bid * 256 + threadIdx.x) * 4;
        float4 v = *(const float4*)(h + i);
        ushort4 o = { f2bf(v.x), f2bf(v.y), f2bf(v.z), f2bf(v.w) };
        *(ushort4*)(h_bf + i) = o;
    } else if (bid < 8192 + 1024) {
        size_t e = ((size_t)(bid - 8192) * 256 + threadIdx.x) * 4;
        int k = (int)(e >> 9), n = (int)(e & 511);
        float4 v = *(const float4*)(W1 + e);
        W1t[(size_t)(n + 0) * K1 + k] = f2bf(v.x);
        W1t[(size_t)(n + 1) * K1 + k] = f2bf(v.y);
        W1t[(size_t)(n + 2) * K1 + k] = f2bf(v.z);
        W1t[(size_t)(n + 3) * K1 + k] = f2bf(v.w);
    } else {
        size_t e = ((size_t)(bid - 9216) * 256 + threadIdx.x) * 4;
        int k = (int)(e >> 8), n = (int)(e & 255);
        float4 v = *(const float4*)(W2 + e);
        W2t[(size_t)(n + 0) * K2 + k] = f2bf(v.x);
        W2t[(size_t)(n + 1) * K2 + k] = f2bf(v.y);
        W2t[(size_t)(n + 2) * K2 + k] = f2bf(v.z);
        W2t[(size_t)(n + 3) * K2 + k] = f2bf(v.w);
    }
}

// ---------------------------------------------------------------------------
// GEMM1 (gathered A): 128x128 tile, BK=32, dbuf LDS, 1 barrier/K-step.
// 1-D grid 1024; decode so blockIdx%8 == batch -> each XCD serves one batch
// (h_bf[b] 2MB + W1t 2MB fit its 4MB L2).
// Bank swizzle: global chunk (sub - row>>1)&3 staged at physical chunk sub;
// readers use physical chunk (quad + row>>1)&3.
// ---------------------------------------------------------------------------
__global__ __launch_bounds__(256) void gemm1_mfma(
    const ushort_t* __restrict__ h_bf, const int* __restrict__ idx,
    const ushort_t* __restrict__ W1t, const float* __restrict__ b1,
    ushort_t* __restrict__ x1_bf)
{
    __shared__ __align__(16) char smem[32768];  // two 16KB buffers (A 8K + B 8K)

    const int tid = threadIdx.x;
    const int w = tid >> 6, lane = tid & 63;
    const int quad = lane >> 4, l16 = lane & 15;
    const int wr = w >> 1, wc = w & 1;

    // XCD-aware decode: batch = bid&7
    const int bid = blockIdx.x;
    const int xcd = bid & 7;
    const int j = bid >> 3;                 // 0..127
    const int n0 = (j & 3) * 128;
    const int m0 = xcd * SWAPS + (j >> 2) * 128;

    // staging coords
    const int row0 = tid >> 2, sub = tid & 3;
    const int cg = (sub - (row0 >> 1)) & 3;       // swizzled global chunk
    const int* ip0 = idx + (size_t)(m0 + row0) * 4;
    const int* ip1 = idx + (size_t)(m0 + row0 + 64) * 4;
    const ushort_t* hb = h_bf + (size_t)xcd * NNODES * DDIM;
    const ushort_t* bA0[4];
    const ushort_t* bA1[4];
    #pragma unroll
    for (int sg = 0; sg < 4; ++sg) {
        bA0[sg] = hb + (size_t)ip0[sg] * DDIM + cg * 8;
        bA1[sg] = hb + (size_t)ip1[sg] * DDIM + cg * 8;
    }
    const ushort_t* bB0 = W1t + (size_t)(n0 + row0) * K1 + cg * 8;
    const ushort_t* bB1 = W1t + (size_t)(n0 + row0 + 64) * K1 + cg * 8;

    // fragment read offsets (lane-constant; physical chunk swizzled)
    int pa[4], pb[4];
    #pragma unroll
    for (int i = 0; i < 4; ++i) {
        const int rA = wr * 64 + i * 16 + l16;
        const int rB = wc * 64 + i * 16 + l16;
        pa[i] = rA * 64 + (((quad + (rA >> 1)) & 3) * 16);
        pb[i] = 8192 + rB * 64 + (((quad + (rB >> 1)) & 3) * 16);
    }

    f32x4 acc[4][4] = {};

    auto stage = [&](int seg, int kk, char* base) {
        const int oA = kk * 32;
        const int oB = seg * 512 + kk * 32;
        glds16(bA0[seg] + oA, base + w * 1024);
        glds16(bA1[seg] + oA, base + 4096 + w * 1024);
        glds16(bB0 + oB,      base + 8192 + w * 1024);
        glds16(bB1 + oB,      base + 12288 + w * 1024);
    };
    auto compute = [&](const char* base) {
        bf16x8 af[4], bfr[4];
        #pragma unroll
        for (int i = 0; i < 4; ++i) {
            af[i]  = *(const bf16x8*)(base + pa[i]);
            bfr[i] = *(const bf16x8*)(base + pb[i]);
        }
        #pragma unroll
        for (int i = 0; i < 4; ++i)
            #pragma unroll
            for (int jj = 0; jj < 4; ++jj)
                acc[i][jj] = __builtin_amdgcn_mfma_f32_16x16x32_bf16(
                    af[i], bfr[jj], acc[i][jj], 0, 0, 0);
    };

    char* buf0 = smem;
    char* buf1 = smem + 16384;

    stage(0, 0, buf0);
    __syncthreads();

    #pragma unroll
    for (int seg = 0; seg < 4; ++seg) {
        #pragma unroll 1
        for (int kk = 0; kk < 16; kk += 2) {
            stage(seg, kk + 1, buf1);      // prefetch next step
            compute(buf0);
            __syncthreads();
            if (kk < 14) stage(seg, kk + 2, buf0);
            else if (seg < 3) stage(seg + 1, 0, buf0);
            compute(buf1);
            __syncthreads();
        }
    }

    // epilogue: C/D layout col=lane&15, row=quad*4+reg
    #pragma unroll
    for (int jj = 0; jj < 4; ++jj) {
        const int n = n0 + wc * 64 + jj * 16 + l16;
        const float bias = b1[n];
        #pragma unroll
        for (int i = 0; i < 4; ++i) {
            f32x4 v = acc[i][jj];
            #pragma unroll
            for (int r = 0; r < 4; ++r) {
                const int m = m0 + wr * 64 + i * 16 + quad * 4 + r;
                x1_bf[(size_t)m * N1 + n] = f2bf(gelu_exact(v[r] + bias));
            }
        }
    }
}

// ---------------------------------------------------------------------------
// GEMM2 + head fused: block = 128 rows x 256 cols (full N2), 4 waves (2x2),
// wave tile 64x128 (4x8 frags). Epilogue: gelu -> dot with W3 in-block ->
// softplus -> out. No x2 materialization, no head kernel.
// Grid 256, XCD-decoded to match gemm1's x1 writes.
// ---------------------------------------------------------------------------
__global__ __launch_bounds__(256) void gemm2_head(
    const ushort_t* __restrict__ x1_bf, const ushort_t* __restrict__ W2t,
    const float* __restrict__ b2, const float* __restrict__ W3,
    const float* __restrict__ b3, float* __restrict__ out)
{
    __shared__ __align__(16) char smem[49152];  // two 24KB buffers (A 8K + B 16K)

    const int tid = threadIdx.x;
    const int w = tid >> 6, lane = tid & 63;
    const int quad = lane >> 4, l16 = lane & 15;
    const int wr = w >> 1, wc = w & 1;

    const int bid = blockIdx.x;
    const int m0 = ((bid & 7) * 32 + (bid >> 3)) * 128;   // batch = bid&7

    const int row0 = tid >> 2, sub = tid & 3;
    const int cg = (sub - (row0 >> 1)) & 3;
    const ushort_t* pA0 = x1_bf + (size_t)(m0 + row0) * K2 + cg * 8;
    const ushort_t* pA1 = x1_bf + (size_t)(m0 + row0 + 64) * K2 + cg * 8;
    const ushort_t* pB0 = W2t + (size_t)(row0) * K2 + cg * 8;
    const ushort_t* pB1 = W2t + (size_t)(row0 + 64) * K2 + cg * 8;
    const ushort_t* pB2 = W2t + (size_t)(row0 + 128) * K2 + cg * 8;
    const ushort_t* pB3 = W2t + (size_t)(row0 + 192) * K2 + cg * 8;

    int pa[4], pb[8];
    #pragma unroll
    for (int i = 0; i < 4; ++i) {
        const int rA = wr * 64 + i * 16 + l16;
        pa[i] = rA * 64 + (((quad + (rA >> 1)) & 3) * 16);
    }
    #pragma unroll
    for (int jj = 0; jj < 8; ++jj) {
        const int rB = wc * 128 + jj * 16 + l16;
        pb[jj] = 8192 + rB * 64 + (((quad + (rB >> 1)) & 3) * 16);
    }

    f32x4 acc[4][8] = {};

    auto stage = [&](int kk, char* base) {
        const int oo = kk * 32;
        glds16(pA0 + oo, base + w * 1024);
        glds16(pA1 + oo, base + 4096 + w * 1024);
        glds16(pB0 + oo, base + 8192 + w * 1024);
        glds16(pB1 + oo, base + 12288 + w * 1024);
        glds16(pB2 + oo, base + 16384 + w * 1024);
        glds16(pB3 + oo, base + 20480 + w * 1024);
    };
    auto compute = [&](const char* base) {
        bf16x8 af[4], bfr[8];
        #pragma unroll
        for (int i = 0; i < 4; ++i) af[i] = *(const bf16x8*)(base + pa[i]);
        #pragma unroll
        for (int jj = 0; jj < 8; ++jj) bfr[jj] = *(const bf16x8*)(base + pb[jj]);
        #pragma unroll
        for (int i = 0; i < 4; ++i)
            #pragma unroll
            for (int jj = 0; jj < 8; ++jj)
                acc[i][jj] = __builtin_amdgcn_mfma_f32_16x16x32_bf16(
                    af[i], bfr[jj], acc[i][jj], 0, 0, 0);
    };

    char* buf0 = smem;
    char* buf1 = smem + 24576;

    stage(0, buf0);
    __syncthreads();

    #pragma unroll 1
    for (int kk = 0; kk < 16; kk += 2) {
        stage(kk + 1, buf1);
        compute(buf0);
        __syncthreads();
        if (kk < 14) stage(kk + 2, buf0);
        compute(buf1);
        __syncthreads();
    }

    // fused epilogue: gelu + dot(W3) + cross-lane/cross-wave reduce + softplus
    float w3r[8], b2r[8];
    #pragma unroll
    for (int jj = 0; jj < 8; ++jj) {
        const int col = wc * 128 + jj * 16 + l16;
        w3r[jj] = W3[col];
        b2r[jj] = b2[col];
    }
    float part[4][4];   // [i][r]
    #pragma unroll
    for (int i = 0; i < 4; ++i)
        #pragma unroll
        for (int r = 0; r < 4; ++r) part[i][r] = 0.0f;
    #pragma unroll
    for (int i = 0; i < 4; ++i)
        #pragma unroll
        for (int jj = 0; jj < 8; ++jj) {
            f32x4 v = acc[i][jj];
            #pragma unroll
            for (int r = 0; r < 4; ++r)
                part[i][r] = fmaf(gelu_exact(v[r] + b2r[jj]), w3r[jj], part[i][r]);
        }
    // reduce over the 16 l16 lanes (same rows, different cols)
    #pragma unroll
    for (int off = 1; off < 16; off <<= 1)
        #pragma unroll
        for (int i = 0; i < 4; ++i)
            #pragma unroll
            for (int r = 0; r < 4; ++r)
                part[i][r] += __shfl_xor(part[i][r], off);

    // combine the two wave-column halves via LDS
    float* redbuf = (float*)smem;   // reuse (all LDS reads completed before last barrier)
    if (wc == 1 && l16 == 0) {
        #pragma unroll
        for (int i = 0; i < 4; ++i)
            #pragma unroll
            for (int r = 0; r < 4; ++r)
                redbuf[wr * 64 + i * 16 + quad * 4 + r] = part[i][r];
    }
    __syncthreads();
    if (wc == 0 && l16 == 0) {
        const float bias3 = b3[0];
        #pragma unroll
        for (int i = 0; i < 4; ++i)
            #pragma unroll
            for (int r = 0; r < 4; ++r) {
                const int rr = wr * 64 + i * 16 + quad * 4 + r;
                out[m0 + rr] = softplus_f(part[i][r] + redbuf[rr] + bias3);
            }
    }
}

// ---------------------------------------------------------------------------
extern "C" void kernel_launch(void* const* d_in, const int* in_sizes, int n_in,
                              void* d_out, int out_size, void* d_ws, size_t ws_size,
                              hipStream_t stream) {
    const float* h   = (const float*)d_in[0];
    const int*   idx = (const int*)d_in[1];
    const float* W1  = (const float*)d_in[2];
    const float* b1  = (const float*)d_in[3];
    const float* W2  = (const float*)d_in[4];
    const float* b2  = (const float*)d_in[5];
    const float* W3  = (const float*)d_in[6];
    const float* b3  = (const float*)d_in[7];
    float* out = (float*)d_out;

    // workspace: h_bf 16MB @0; W1t 2MB @16M; W2t 256KB @18M; x1_bf 32MB @18.25M
    char* ws = (char*)d_ws;
    ushort_t* h_bf  = (ushort_t*)ws;
    ushort_t* W1t   = (ushort_t*)(ws + (16u << 20));
    ushort_t* W2t   = (ushort_t*)(ws + (18u << 20));
    ushort_t* x1_bf = (ushort_t*)(ws + (18u << 20) + (256u << 10));

    convert_kernel<<<9344, 256, 0, stream>>>(h, W1, W2, h_bf, W1t, W2t);
    gemm1_mfma<<<1024, 256, 0, stream>>>(h_bf, idx, W1t, b1, x1_bf);
    gemm2_head<<<256, 256, 0, stream>>>(x1_bf, W2t, b2, W3, b3, out);
}

// Round 4
// 199.415 us; speedup vs baseline: 1.7328x; 1.7328x over previous
//
#include <hip/hip_runtime.h>
#include <math.h>

// Problem constants: B=8, N=2048, D=512, S=4096
#define BATCH 8
#define NNODES 2048
#define DDIM 512
#define SWAPS 4096
#define M_TOTAL (BATCH * SWAPS)   // 32768
#define MD (BATCH * NNODES)       // 16384 dense rows
#define KD DDIM                   // 512 (dense GEMM K)
#define ND (4 * DDIM)             // 2048 (dense GEMM N = 4 segs x 512)
#define K2 DDIM                   // 512
#define N2 (DDIM / 2)             // 256

typedef __attribute__((ext_vector_type(8))) __bf16 bf16x8;   // MFMA A/B frag
typedef __attribute__((ext_vector_type(4))) float f32x4;      // MFMA C/D frag
typedef __attribute__((ext_vector_type(8))) unsigned short us8;
typedef unsigned short ushort_t;

__device__ __forceinline__ float gelu_exact(float x) {
    return 0.5f * x * (1.0f + erff(x * 0.70710678118654752440f));
}
__device__ __forceinline__ float softplus_f(float x) {
    return fmaxf(x, 0.0f) + log1pf(expf(-fabsf(x)));
}
__device__ __forceinline__ unsigned short f2bf(float f) {
    unsigned int u = __builtin_bit_cast(unsigned int, f);
    u += 0x7FFFu + ((u >> 16) & 1u);
    return (unsigned short)(u >> 16);
}
__device__ __forceinline__ float bf2f(unsigned short s) {
    return __builtin_bit_cast(float, (unsigned int)s << 16);
}
__device__ __forceinline__ void glds16(const void* g, void* l) {
    __builtin_amdgcn_global_load_lds(
        (const __attribute__((address_space(1))) void*)g,
        (__attribute__((address_space(3))) void*)l, 16, 0, 0);
}

// ---------------------------------------------------------------------------
// convert: h -> h_bf (bf16);  W1[k][n] -> W1pt[j][d] bf16 where j = (k/512)*512+n,
// d = k%512 (fragment-ready K-major for the dense GEMM);  W2 -> W2t bf16 K-major.
// ---------------------------------------------------------------------------
__global__ __launch_bounds__(256) void convert_kernel(
    const float* __restrict__ h, const float* __restrict__ W1,
    const float* __restrict__ W2, ushort_t* __restrict__ h_bf,
    ushort_t* __restrict__ W1pt, ushort_t* __restrict__ W2t)
{
    const int bid = blockIdx.x;
    if (bid < 8192) {                       // h: 8M elems
        size_t i = ((size_t)bid * 256 + threadIdx.x) * 4;
        float4 v = *(const float4*)(h + i);
        ushort4 o = { f2bf(v.x), f2bf(v.y), f2bf(v.z), f2bf(v.w) };
        *(ushort4*)(h_bf + i) = o;
    } else if (bid < 8192 + 1024) {         // W1: 1M elems (2048 x 512 row-major)
        size_t e = ((size_t)(bid - 8192) * 256 + threadIdx.x) * 4;
        const int k = (int)(e >> 9), n = (int)(e & 511);
        const int sg = k >> 9, d = k & 511;
        const int j = sg * 512 + n;
        float4 v = *(const float4*)(W1 + e);
        W1pt[(size_t)(j + 0) * KD + d] = f2bf(v.x);
        W1pt[(size_t)(j + 1) * KD + d] = f2bf(v.y);
        W1pt[(size_t)(j + 2) * KD + d] = f2bf(v.z);
        W1pt[(size_t)(j + 3) * KD + d] = f2bf(v.w);
    } else {                                // W2: 131072 elems (512 x 256)
        size_t e = ((size_t)(bid - 9216) * 256 + threadIdx.x) * 4;
        const int k = (int)(e >> 8), n = (int)(e & 255);
        float4 v = *(const float4*)(W2 + e);
        W2t[(size_t)(n + 0) * K2 + k] = f2bf(v.x);
        W2t[(size_t)(n + 1) * K2 + k] = f2bf(v.y);
        W2t[(size_t)(n + 2) * K2 + k] = f2bf(v.z);
        W2t[(size_t)(n + 3) * K2 + k] = f2bf(v.w);
    }
}

// ---------------------------------------------------------------------------
// Dense GEMM1: P[m][j] = bf16( h_bf[m,:] @ W1pt[j,:] ), M=16384, N=2048, K=512.
// m97-pattern: 128x128 tile, BK=32, single-buffer, 2 barriers/step, glds16
// width-16 staging, bank-swizzled LDS chunks. XCD swizzle: bid&7 = batch
// (h_bf[b] 2MB + W1pt 2MB fit one XCD L2). No bias/activation (raw partials).
// ---------------------------------------------------------------------------
__global__ __launch_bounds__(256) void gemm1_dense(
    const ushort_t* __restrict__ h_bf, const ushort_t* __restrict__ W1pt,
    ushort_t* __restrict__ P)
{
    __shared__ __align__(16) char smem[16384];   // A 8KB @0, B 8KB @8192

    const int tid = threadIdx.x;
    const int w = tid >> 6, lane = tid & 63;
    const int quad = lane >> 4, l16 = lane & 15;
    const int wr = w >> 1, wc = w & 1;

    // XCD decode: 2048 blocks; batch = bid&7, then 16 m-tiles x 16 n-tiles
    const int bid = blockIdx.x;
    const int xcd = bid & 7;
    const int r = bid >> 3;
    const int m0 = xcd * NNODES + (r & 15) * 128;
    const int n0 = (r >> 4) * 128;

    // staging coords with chunk swizzle (see r3: stage global chunk cg at
    // physical chunk sub; readers use physical chunk (quad+row>>1)&3)
    const int row0 = tid >> 2, sub = tid & 3;
    const int cg = (sub - (row0 >> 1)) & 3;
    const ushort_t* bA0 = h_bf + (size_t)(m0 + row0) * KD + cg * 8;
    const ushort_t* bA1 = h_bf + (size_t)(m0 + row0 + 64) * KD + cg * 8;
    const ushort_t* bB0 = W1pt + (size_t)(n0 + row0) * KD + cg * 8;
    const ushort_t* bB1 = W1pt + (size_t)(n0 + row0 + 64) * KD + cg * 8;

    char* ldsA0 = smem + w * 1024;
    char* ldsA1 = smem + 4096 + w * 1024;
    char* ldsB0 = smem + 8192 + w * 1024;
    char* ldsB1 = smem + 12288 + w * 1024;

    int pa[4], pb[4];
    #pragma unroll
    for (int i = 0; i < 4; ++i) {
        const int rA = wr * 64 + i * 16 + l16;
        const int rB = wc * 64 + i * 16 + l16;
        pa[i] = rA * 64 + (((quad + (rA >> 1)) & 3) * 16);
        pb[i] = 8192 + rB * 64 + (((quad + (rB >> 1)) & 3) * 16);
    }

    f32x4 acc[4][4] = {};

    for (int kt = 0; kt < 16; ++kt) {
        const int oo = kt * 32;
        glds16(bA0 + oo, ldsA0);
        glds16(bA1 + oo, ldsA1);
        glds16(bB0 + oo, ldsB0);
        glds16(bB1 + oo, ldsB1);
        __syncthreads();
        bf16x8 af[4], bfr[4];
        #pragma unroll
        for (int i = 0; i < 4; ++i) {
            af[i]  = *(const bf16x8*)(smem + pa[i]);
            bfr[i] = *(const bf16x8*)(smem + pb[i]);
        }
        #pragma unroll
        for (int i = 0; i < 4; ++i)
            #pragma unroll
            for (int jj = 0; jj < 4; ++jj)
                acc[i][jj] = __builtin_amdgcn_mfma_f32_16x16x32_bf16(
                    af[i], bfr[jj], acc[i][jj], 0, 0, 0);
        __syncthreads();
    }

    // epilogue: raw bf16 partials; C/D layout col=lane&15, row=quad*4+reg
    #pragma unroll
    for (int jj = 0; jj < 4; ++jj) {
        const int n = n0 + wc * 64 + jj * 16 + l16;
        #pragma unroll
        for (int i = 0; i < 4; ++i) {
            f32x4 v = acc[i][jj];
            #pragma unroll
            for (int rr = 0; rr < 4; ++rr) {
                const int m = m0 + wr * 64 + i * 16 + quad * 4 + rr;
                P[(size_t)m * ND + n] = f2bf(v[rr]);
            }
        }
    }
}

// ---------------------------------------------------------------------------
// gather_sum: x1[m][n] = bf16(gelu( b1[n] + sum_sg P[b, idx[m][sg], sg*512+n] ))
// One wave per swap row; lane covers n = lane*8..+7. Fully coalesced 1KB reads.
// ---------------------------------------------------------------------------
__global__ __launch_bounds__(256) void gather_sum_kernel(
    const ushort_t* __restrict__ P, const int* __restrict__ idx,
    const float* __restrict__ b1, ushort_t* __restrict__ x1_bf)
{
    const int wave = threadIdx.x >> 6, lane = threadIdx.x & 63;
    const int m = blockIdx.x * 4 + wave;          // 0..32767
    const int b = m >> 12;                        // batch
    const int4 iv = *(const int4*)(idx + (size_t)m * 4);
    const ushort_t* Pb = P + (size_t)b * NNODES * ND;
    const int n = lane * 8;

    float s[8];
    {
        float4 ba = *(const float4*)(b1 + n);
        float4 bb = *(const float4*)(b1 + n + 4);
        s[0] = ba.x; s[1] = ba.y; s[2] = ba.z; s[3] = ba.w;
        s[4] = bb.x; s[5] = bb.y; s[6] = bb.z; s[7] = bb.w;
    }
    const int nodes[4] = { iv.x, iv.y, iv.z, iv.w };
    #pragma unroll
    for (int sg = 0; sg < 4; ++sg) {
        us8 v = *(const us8*)(Pb + (size_t)nodes[sg] * ND + sg * 512 + n);
        #pragma unroll
        for (int t = 0; t < 8; ++t) s[t] += bf2f(v[t]);
    }
    ushort4 o0 = { f2bf(gelu_exact(s[0])), f2bf(gelu_exact(s[1])),
                   f2bf(gelu_exact(s[2])), f2bf(gelu_exact(s[3])) };
    ushort4 o1 = { f2bf(gelu_exact(s[4])), f2bf(gelu_exact(s[5])),
                   f2bf(gelu_exact(s[6])), f2bf(gelu_exact(s[7])) };
    *(ushort4*)(x1_bf + (size_t)m * K2 + n) = o0;
    *(ushort4*)(x1_bf + (size_t)m * K2 + n + 4) = o1;
}

// ---------------------------------------------------------------------------
// GEMM2 (dense, r2-proven): x2 = gelu( x1 @ W2 + b2 ), M=32768, K=512, N=256
// ---------------------------------------------------------------------------
__global__ __launch_bounds__(256) void gemm2_mfma(
    const ushort_t* __restrict__ x1_bf, const ushort_t* __restrict__ W2t,
    const float* __restrict__ b2, float* __restrict__ x2)
{
    __shared__ __align__(16) char smem[16384];

    const int tid = threadIdx.x;
    const int w = tid >> 6, lane = tid & 63;
    const int quad = lane >> 4, l16 = lane & 15;
    const int wr = w >> 1, wc = w & 1;
    const int m0 = blockIdx.y * 128, n0 = blockIdx.x * 128;

    const int row0 = tid >> 2, sub = tid & 3;
    const int cg = (sub - (row0 >> 1)) & 3;
    const ushort_t* bA0 = x1_bf + (size_t)(m0 + row0) * K2 + cg * 8;
    const ushort_t* bA1 = x1_bf + (size_t)(m0 + row0 + 64) * K2 + cg * 8;
    const ushort_t* bB0 = W2t + (size_t)(n0 + row0) * K2 + cg * 8;
    const ushort_t* bB1 = W2t + (size_t)(n0 + row0 + 64) * K2 + cg * 8;

    char* ldsA0 = smem + w * 1024;
    char* ldsA1 = smem + 4096 + w * 1024;
    char* ldsB0 = smem + 8192 + w * 1024;
    char* ldsB1 = smem + 12288 + w * 1024;

    int pa[4], pb[4];
    #pragma unroll
    for (int i = 0; i < 4; ++i) {
        const int rA = wr * 64 + i * 16 + l16;
        const int rB = wc * 64 + i * 16 + l16;
        pa[i] = rA * 64 + (((quad + (rA >> 1)) & 3) * 16);
        pb[i] = 8192 + rB * 64 + (((quad + (rB >> 1)) & 3) * 16);
    }

    f32x4 acc[4][4] = {};

    for (int kt = 0; kt < 16; ++kt) {
        const int oo = kt * 32;
        glds16(bA0 + oo, ldsA0);
        glds16(bA1 + oo, ldsA1);
        glds16(bB0 + oo, ldsB0);
        glds16(bB1 + oo, ldsB1);
        __syncthreads();
        bf16x8 af[4], bfr[4];
        #pragma unroll
        for (int i = 0; i < 4; ++i) {
            af[i]  = *(const bf16x8*)(smem + pa[i]);
            bfr[i] = *(const bf16x8*)(smem + pb[i]);
        }
        #pragma unroll
        for (int i = 0; i < 4; ++i)
            #pragma unroll
            for (int jj = 0; jj < 4; ++jj)
                acc[i][jj] = __builtin_amdgcn_mfma_f32_16x16x32_bf16(
                    af[i], bfr[jj], acc[i][jj], 0, 0, 0);
        __syncthreads();
    }

    #pragma unroll
    for (int jj = 0; jj < 4; ++jj) {
        const int n = n0 + wc * 64 + jj * 16 + l16;
        const float bias = b2[n];
        #pragma unroll
        for (int i = 0; i < 4; ++i) {
            f32x4 v = acc[i][jj];
            #pragma unroll
            for (int rr = 0; rr < 4; ++rr) {
                const int m = m0 + wr * 64 + i * 16 + quad * 4 + rr;
                x2[(size_t)m * N2 + n] = gelu_exact(v[rr] + bias);
            }
        }
    }
}

// ---------------------------------------------------------------------------
// Head: out[m] = softplus( dot(x2[m], W3) + b3 ). One wave per row.
// ---------------------------------------------------------------------------
__global__ __launch_bounds__(256) void head_kernel(
    const float* __restrict__ x2, const float* __restrict__ W3,
    const float* __restrict__ b3, float* __restrict__ out)
{
    const int wave = threadIdx.x >> 6;
    const int lane = threadIdx.x & 63;
    const int m = blockIdx.x * 4 + wave;
    if (m >= M_TOTAL) return;

    const float* row = x2 + (size_t)m * N2;
    float s = 0.0f;
    #pragma unroll
    for (int k = 0; k < N2; k += 64) s = fmaf(row[k + lane], W3[k + lane], s);
    #pragma unroll
    for (int off = 32; off > 0; off >>= 1) s += __shfl_down(s, off);
    if (lane == 0) out[m] = softplus_f(s + b3[0]);
}

// ---------------------------------------------------------------------------
// Workspace layout (aliased; peak 96.25 MB):
//   P     @ 0      : 16384*2048*2 = 64 MB   (dead after gather_sum)
//   x2    @ 0      : 32768*256*4  = 32 MB   (overlays dead P)
//   h_bf  @ 64 MB  : 16 MB  (dead after gemm1_dense; overlaid by x1_bf)
//   W1pt  @ 80 MB  :  2 MB  (dead after gemm1_dense; overlaid by x1_bf)
//   x1_bf @ 64 MB  : 32 MB  (written by gather_sum after h_bf/W1pt dead)
//   W2t   @ 96 MB  : 256 KB
// ---------------------------------------------------------------------------
extern "C" void kernel_launch(void* const* d_in, const int* in_sizes, int n_in,
                              void* d_out, int out_size, void* d_ws, size_t ws_size,
                              hipStream_t stream) {
    const float* h   = (const float*)d_in[0];
    const int*   idx = (const int*)d_in[1];
    const float* W1  = (const float*)d_in[2];
    const float* b1  = (const float*)d_in[3];
    const float* W2  = (const float*)d_in[4];
    const float* b2  = (const float*)d_in[5];
    const float* W3  = (const float*)d_in[6];
    const float* b3  = (const float*)d_in[7];
    float* out = (float*)d_out;

    char* ws = (char*)d_ws;
    ushort_t* P     = (ushort_t*)ws;
    float*    x2    = (float*)ws;
    ushort_t* h_bf  = (ushort_t*)(ws + (64u << 20));
    ushort_t* W1pt  = (ushort_t*)(ws + (80u << 20));
    ushort_t* x1_bf = (ushort_t*)(ws + (64u << 20));
    ushort_t* W2t   = (ushort_t*)(ws + (96u << 20));

    convert_kernel<<<9344, 256, 0, stream>>>(h, W1, W2, h_bf, W1pt, W2t);
    gemm1_dense<<<2048, 256, 0, stream>>>(h_bf, W1pt, P);
    gather_sum_kernel<<<M_TOTAL / 4, 256, 0, stream>>>(P, idx, b1, x1_bf);
    gemm2_mfma<<<dim3(N2 / 128, M_TOTAL / 128), 256, 0, stream>>>(x1_bf, W2t, b2, x2);
    head_kernel<<<M_TOTAL / 4, 256, 0, stream>>>(x2, W3, b3, out);
}